// Round 6
// baseline (7790.759 us; speedup 1.0000x reference)
//
#include <hip/hip_runtime.h>
#include <math.h>

// TemporalPredictionNetwork: L=4, S=512, H=1024, B=1.
// Round-11: round-8 verified stage-parallel dataflow + REPRESENTATIVE-ENTRY
// PRE-SCAN (congestion control), after two container failures on the
// sentinel rewrite. Producer side, init, memory layout, and dependency
// edges are byte-identical to the verified round-8 kernel; the only change
// is consumer-side: thread 0 polls ONE existing tag per producer WG (8-32
// words), then __syncthreads (barrier waiters generate no fabric traffic),
// then all threads do single-shot tagged loads. Round-8's per-entry pollt
// retry stays as a safety net. This cuts poll agents ~500x on the exact
// cache lines producers are writing (round-8's diagnosed bottleneck:
// 13.5us/round II from poll-storm ping-pong at the coherence point).
// All spins bounded (pollt ~30ms, scans ~2ms): a sync bug ends as a wrong
// answer with counters, never a hang.
#define NLVL 4
#define HDIM 1024
#define SEQ  512
#define THREADS 512
#define NWAVES (THREADS / 64)
#define NWG (48 + 3 * 64)    // lvl0: 8+8+32; lvl1-3: 8+8+8+8+32

typedef unsigned short u16;
typedef unsigned int   u32;
typedef unsigned long long u64;

// ---- tagged workspace layout (u64 units) ----
// entry = {value f32 in [31:0], tag u32 in [63:32]}; round-r write -> tag r+1
#define TG_HS4   0                       // [4][NLVL][HDIM]
#define TG_ENC4  16384                   // [4][NLVL][HDIM]
#define TG_T1R   32768                   // [NLVL][4][HDIM]
#define TG_ERRR  49152                   // [NLVL][4][HDIM]
#define TG_T2R   65536                   // [NLVL][4][HDIM]
#define TG_DPR   81920                   // [NLVL][4] slots, 8-u64 stride
#define TG_PROG  82048                   // [20 groups][32 wgs], 8-u64 stride
#define TG_FE    87168                   // [NLVL][8]
#define TG_FIN   87200
#define TG_END   87208

// bf16 weight region (u16 units) at byte offset TG_END*8
#define BW_SQ   (NLVL * HDIM * HDIM)
#define BW_P1   0
#define BW_P2   (BW_P1 + BW_SQ)
#define BW_E1   (BW_P2 + BW_SQ)
#define BW_E2   (BW_E1 + BW_SQ)
#define BW_IH   (BW_E2 + BW_SQ)          // L x 3H x H (gates i,g,o)
#define BW_IH_N (NLVL * 3 * HDIM * HDIM)
#define BW_TOTAL (BW_IH + BW_IH_N)

#define POLL_CAP  (1 << 16)              // ~30 ms worst case
#define GSCAN_CAP (1 << 13)              // ~2 ms worst case

__device__ __forceinline__ float gelu_f(float x) {
  return 0.5f * x * (1.0f + erff(x * 0.70710678118654752f));
}
__device__ __forceinline__ float sigmoid_f(float x) {
  return 1.0f / (1.0f + __expf(-x));
}

__device__ __forceinline__ float gload(const float* p) {
  return __hip_atomic_load((float*)p, __ATOMIC_RELAXED, __HIP_MEMORY_SCOPE_AGENT);
}
__device__ __forceinline__ void gstore(float* p, float v) {
  __hip_atomic_store(p, v, __ATOMIC_RELAXED, __HIP_MEMORY_SCOPE_AGENT);
}
__device__ __forceinline__ u32 uload(const u32* p) {
  return __hip_atomic_load((u32*)p, __ATOMIC_RELAXED, __HIP_MEMORY_SCOPE_AGENT);
}
__device__ __forceinline__ u64 tload(const u64* p) {
  return __hip_atomic_load((u64*)p, __ATOMIC_RELAXED, __HIP_MEMORY_SCOPE_AGENT);
}
__device__ __forceinline__ void tstore(u64* p, float v, u32 tag) {
  u64 x = ((u64)tag << 32) | (u64)__float_as_uint(v);
  __hip_atomic_store(p, x, __ATOMIC_RELAXED, __HIP_MEMORY_SCOPE_AGENT);
}
__device__ __forceinline__ float tval(u64 x) { return __uint_as_float((u32)x); }
__device__ __forceinline__ u32   ttag(u64 x) { return (u32)(x >> 32); }

// safety-net tag poll: 1-load fast path (pre-scan already certified);
// bounded s_sleep retry otherwise
__device__ __forceinline__ u64 pollt(const u64* p, u32 need) {
  u64 x = tload(p);
  if (ttag(x) >= need) return x;
  int spin = 0;
  for (;;) {
    x = tload(p);
    if (ttag(x) >= need) return x;
    if (++spin > 16) {
      __builtin_amdgcn_s_sleep(1);
      if (spin > POLL_CAP) return x;
    }
  }
}

// thread-0 pre-scan: poll the tag of one representative entry per producer
// WG (stride = entries per producer WG). Cached min so satisfied edges cost
// zero loads. Bounded; correctness still guaranteed by per-entry pollt.
template <int N, int STRIDE>
__device__ __forceinline__ u32 repscan(const u64* basep, u32 need, u32 cached) {
  if (cached >= need) return cached;
  int spin = 0;
  for (;;) {
    u32 mn = 0xffffffffu;
#pragma unroll
    for (int w = 0; w < N; ++w) {
      u32 tg_ = ttag(tload(basep + (size_t)w * STRIDE));
      mn = (tg_ < mn) ? tg_ : mn;
    }
    if (mn >= need) return mn;
    __builtin_amdgcn_s_sleep(1);
    if (++spin > GSCAN_CAP) return need;
  }
}

// min-scan guard over a consumer group's progress words (WAR back-pressure)
template <int N>
__device__ __forceinline__ void gscan(const u64* pb, u32 need) {
  int spin = 0;
  for (;;) {
    u32 mn = 0xffffffffu;
#pragma unroll
    for (int w = 0; w < N; ++w) {
      u32 c = uload((const u32*)(pb + (size_t)w * 8));
      mn = (c < mn) ? c : mn;
    }
    if (mn >= need) return;
    __builtin_amdgcn_s_sleep(2);
    if (++spin > GSCAN_CAP) return;
  }
}

__device__ __forceinline__ float wredux_all(float v) {   // butterfly: all lanes get sum
#pragma unroll
  for (int off = 32; off; off >>= 1) v += __shfl_xor(v, off, 64);
  return v;
}

__device__ __forceinline__ float dot4f(float4 a, float4 x, float acc) {
  return fmaf(a.x, x.x, fmaf(a.y, x.y, fmaf(a.z, x.z, fmaf(a.w, x.w, acc))));
}
__device__ __forceinline__ float bflo(u32 u) { return __uint_as_float(u << 16); }
__device__ __forceinline__ float bfhi(u32 u) { return __uint_as_float(u & 0xffff0000u); }
__device__ __forceinline__ float bdot(uint2 u, float4 x, float acc) {
  acc = fmaf(bflo(u.x), x.x, acc); acc = fmaf(bfhi(u.x), x.y, acc);
  acc = fmaf(bflo(u.y), x.z, acc); acc = fmaf(bfhi(u.y), x.w, acc);
  return acc;
}
__device__ __forceinline__ u16 f2bf(float f) {
  u32 b = __float_as_uint(f);
  return (u16)((b + 0x7fffu + ((b >> 16) & 1u)) >> 16);
}

// fill LDS x-vector from tagged (st) or plain (sp) 1024-vector (single-shot)
__device__ __forceinline__ void fill_x(const u64* st, const float* sp, u32 need,
                                       float* xb) {
  const int i0 = threadIdx.x, i1 = threadIdx.x + THREADS;
  float v0, v1;
  if (st) { v0 = tval(pollt(st + i0, need)); v1 = tval(pollt(st + i1, need)); }
  else    { v0 = sp[i0]; v1 = sp[i1]; }
  xb[i0] = v0; xb[i1] = v1;
}

template <bool BF16>
__device__ __forceinline__ void loadW16(uint2 (&Wr)[16][4], const u16* Wb,
                                        int base, int lane) {
  if constexpr (BF16) {
#pragma unroll
    for (int k = 0; k < 16; ++k) {
      const uint2* w = (const uint2*)(Wb + (size_t)(base + k) * HDIM);
      Wr[k][0] = w[lane]; Wr[k][1] = w[lane + 64];
      Wr[k][2] = w[lane + 128]; Wr[k][3] = w[lane + 192];
    }
  }
}

// 16-row matvec; returns o_j in lane j (j<16)
template <bool BF16>
__device__ __forceinline__ float dot16_keep(const uint2 (&Wr)[16][4],
                                            const float* Wf, int base,
                                            const float4* x4, int lane) {
  float4 X0 = x4[lane], X1 = x4[lane + 64], X2 = x4[lane + 128], X3 = x4[lane + 192];
  float keep = 0.f;
#pragma unroll
  for (int k = 0; k < 16; ++k) {
    float a;
    if constexpr (BF16) {
      a = bdot(Wr[k][0], X0, 0.f); a = bdot(Wr[k][1], X1, a);
      a = bdot(Wr[k][2], X2, a);  a = bdot(Wr[k][3], X3, a);
    } else {
      const float4* w = (const float4*)(Wf + (size_t)(base + k) * HDIM);
      float4 A0 = w[lane], A1 = w[lane + 64], A2 = w[lane + 128], A3 = w[lane + 192];
      a = dot4f(A0, X0, 0.f); a = dot4f(A1, X1, a);
      a = dot4f(A2, X2, a);   a = dot4f(A3, X3, a);
    }
    a = wredux_all(a);
    keep = (lane == k) ? a : keep;
  }
  return keep;
}

extern "C" __global__ void tpn_init(u64* tg) {
  int i = blockIdx.x * blockDim.x + threadIdx.x;
  int n = blockDim.x * gridDim.x;
  // hs: value 0, tag = lvl (satisfies P5@r=lvl reading zero initial state)
  for (int k = i; k < 4 * NLVL * HDIM; k += n) {
    u32 lvl = (u32)((k / HDIM) % NLVL);
    tg[TG_HS4 + k] = ((u64)lvl) << 32;
  }
  for (int k = i; k < 4 * NLVL * HDIM; k += n) tg[TG_ENC4 + k] = 0ull;
  for (int k = i; k < 3 * NLVL * 4 * HDIM; k += n) tg[TG_T1R + k] = 0ull; // t1,err,t2
  for (int k = i; k < (TG_END - TG_DPR); k += n) tg[TG_DPR + k] = 0ull;
}

extern "C" __global__ void cvt_sq(const float* __restrict__ src,
                                  u16* __restrict__ dst, int n) {
  int i = blockIdx.x * blockDim.x + threadIdx.x;
  int stride = blockDim.x * gridDim.x;
  for (; i < n; i += stride) dst[i] = f2bf(src[i]);
}

// wih [L][4H][H] -> compact [L][3H][H] keeping gates {i=0, g=2, o=3}
extern "C" __global__ void cvt_ih(const float* __restrict__ wih,
                                  u16* __restrict__ dst) {
  int i = blockIdx.x * blockDim.x + threadIdx.x;
  int stride = blockDim.x * gridDim.x;
  const int per_lvl = 3 * HDIM * HDIM;
  for (; i < NLVL * per_lvl; i += stride) {
    int l = i / per_lvl;
    int rem = i - l * per_lvl;
    int gd = rem / (HDIM * HDIM);
    int rr = rem - gd * (HDIM * HDIM);
    int gs = (gd == 0) ? 0 : gd + 1;
    dst[i] = f2bf(wih[((size_t)(l * 4 + gs) * HDIM) * HDIM + rr]);
  }
}

__device__ __forceinline__ u64* progp(u64* tg, int l, int ph) {
  return tg + TG_PROG + ((size_t)(l * 5 + ph) * 32) * 8;
}
__device__ __forceinline__ void pub(u64* w, u32 v) {
  __hip_atomic_store((u32*)w, v, __ATOMIC_RELAXED, __HIP_MEMORY_SCOPE_AGENT);
}

template <bool BF16>
__global__ void __launch_bounds__(THREADS) tpn_main_t(
    const float* __restrict__ observed,
    const float* __restrict__ pw1, const float* __restrict__ pb1,
    const float* __restrict__ pw2, const float* __restrict__ pb2,
    const float* __restrict__ ew1, const float* __restrict__ eb1,
    const float* __restrict__ ew2, const float* __restrict__ eb2,
    const float* __restrict__ qw,  const float* __restrict__ qb,
    const float* __restrict__ wih, const float* __restrict__ bih,
    const float* __restrict__ bhh,
    float* __restrict__ out, u64* __restrict__ tg,
    const u16* __restrict__ bw)
{
  __shared__ __align__(16) float xl[2][HDIM];
  __shared__ float sred[NWAVES];
  const int bx = blockIdx.x;
  int lvl, phase, wgl;
  if (bx < 48) {
    lvl = 0;
    if (bx < 8)       { phase = 2; wgl = bx; }
    else if (bx < 16) { phase = 3; wgl = bx - 8; }
    else              { phase = 4; wgl = bx - 16; }
  } else {
    int b = bx - 48; lvl = 1 + b / 64; int o = b % 64;
    if (o < 8)       { phase = 0; wgl = o; }
    else if (o < 16) { phase = 1; wgl = o - 8; }
    else if (o < 24) { phase = 2; wgl = o - 16; }
    else if (o < 32) { phase = 3; wgl = o - 24; }
    else             { phase = 4; wgl = o - 32; }
  }
  const int wave = threadIdx.x >> 6, lane = threadIdx.x & 63;

  u64* hsT  = tg + TG_HS4;
  u64* encT = tg + TG_ENC4;
  u64* myprog = progp(tg, lvl, phase) + (size_t)wgl * 8;

  if (phase == 4) {
    // ================= P5: LSTM h-chain =================
    const int wid = wgl * NWAVES + wave;        // 0..255
    const int b4 = wid * 4;                     // 4 h-rows per wave
    const u16* Bih = bw + BW_IH + (size_t)lvl * 3 * HDIM * HDIM;
    const float* Wih = wih + (size_t)lvl * 4 * HDIM * HDIM;
    const float* bi = bih + lvl * 4 * HDIM;
    const float* bh = bhh + lvl * 4 * HDIM;
    uint2 Wr[12][4];
    if constexpr (BF16) {
#pragma unroll
      for (int k = 0; k < 12; ++k) {
        const int hr = k / 3, g = k % 3;
        const uint2* w = (const uint2*)(Bih + ((size_t)g * HDIM + b4 + hr) * HDIM);
        Wr[k][0] = w[lane]; Wr[k][1] = w[lane + 64];
        Wr[k][2] = w[lane + 128]; Wr[k][3] = w[lane + 192];
      }
    }
    float mb0 = 0.f, mb1 = 0.f, mb2 = 0.f;
    if (lane < 4) {
      const int rr = b4 + lane;
      mb0 = bi[rr] + bh[rr];
      mb1 = bi[2 * HDIM + rr] + bh[2 * HDIM + rr];
      mb2 = bi[3 * HDIM + rr] + bh[3 * HDIM + rr];
    }
    float fe_local = 0.f;
    u32 pcE = 0, pcH = 0, pcD = 0;
    for (int r = lvl; r < lvl + SEQ; ++r) {
      float* xb = xl[r & 1];
      const u64* el = encT + (size_t)((r & 3) * NLVL + lvl) * HDIM;
      const u64* hold = hsT + (size_t)(((r - 1) & 3) * NLVL + lvl) * HDIM;
      const u64* dps = tg + TG_DPR + ((size_t)lvl * 4 + (r & 3)) * 8;
      // --- thread-0 representative pre-scan + WAR guards ---
      if (threadIdx.x == 0) {
        pcE = repscan<8, 128>(el, (u32)(r + 1), pcE);     // enc: 8 producer WGs
        pcH = repscan<32, 32>(hold, (u32)r, pcH);         // h: 32 producer WGs
        pcD = repscan<1, 1>(dps, (u32)(r + 1), pcD);      // dprec
        if (r - lvl >= 4) {
          gscan<32>(progp(tg, lvl, 4), (u32)(r - 2));          // h ring (own reads)
          if (lvl < 3) gscan<8>(progp(tg, lvl + 1, 0), (u32)(r - 2)); // P1 above
        }
      }
      __syncthreads();
      // --- single-shot fills ---
      const int i0 = threadIdx.x, i1 = threadIdx.x + THREADS;
      u64 E0 = pollt(el + i0, (u32)(r + 1));
      u64 E1 = pollt(el + i1, (u32)(r + 1));
      u64 H0 = pollt(hold + i0, (u32)r);
      u64 H1 = pollt(hold + i1, (u32)r);
      u64 D = pollt(dps, (u32)(r + 1));
      float pr = sigmoid_f(tval(D));
      float e0 = tval(E0), e1 = tval(E1);
      xb[i0] = fmaf(pr, e0, tval(H0));
      xb[i1] = fmaf(pr, e1, tval(H1));
      __syncthreads();
      if (threadIdx.x == 0) pub(myprog, (u32)(r + 1));
      // --- compute ---
      const float4* x4 = (const float4*)xb;
      float4 X0 = x4[lane], X1 = x4[lane + 64], X2 = x4[lane + 128], X3 = x4[lane + 192];
      float dk0 = 0.f, dk1 = 0.f, dk2 = 0.f;
#pragma unroll
      for (int k = 0; k < 12; ++k) {
        const int hr = k / 3, g = k % 3;
        float a;
        if constexpr (BF16) {
          a = bdot(Wr[k][0], X0, 0.f); a = bdot(Wr[k][1], X1, a);
          a = bdot(Wr[k][2], X2, a);  a = bdot(Wr[k][3], X3, a);
        } else {
          const int gsel = (g == 0) ? 0 : (g + 1);
          const float4* w =
              (const float4*)(Wih + ((size_t)gsel * HDIM + b4 + hr) * HDIM);
          float4 A0 = w[lane], A1 = w[lane + 64], A2 = w[lane + 128], A3 = w[lane + 192];
          a = dot4f(A0, X0, 0.f); a = dot4f(A1, X1, a);
          a = dot4f(A2, X2, a);   a = dot4f(A3, X3, a);
        }
        a = wredux_all(a);
        if (g == 0)      dk0 = (lane == hr) ? a : dk0;
        else if (g == 1) dk1 = (lane == hr) ? a : dk1;
        else             dk2 = (lane == hr) ? a : dk2;
      }
      if (lane < 4) {
        float gi = sigmoid_f(dk0 + mb0);
        float gg = tanhf(dk1 + mb1);
        float go = sigmoid_f(dk2 + mb2);
        tstore(hsT + (size_t)((r & 3) * NLVL + lvl) * HDIM + b4 + lane,
               go * tanhf(gi * gg), (u32)(r + 1));
      }
      if (wgl == 0) {   // fe += prec * sum(enc^2)
        float s = fmaf(e0, e0, e1 * e1);
        s = wredux_all(s);
        if (lane == 0) sred[wave] = s;
        __syncthreads();
        if (threadIdx.x == 0) {
          float tot = 0.f;
#pragma unroll
          for (int k = 0; k < NWAVES; ++k) tot += sred[k];
          fe_local += pr * tot;
        }
        __syncthreads();
      }
    }
    if (wgl == 0 && threadIdx.x == 0) {
      gstore((float*)(tg + TG_FE + (size_t)lvl * 8), fe_local);
      asm volatile("s_waitcnt vmcnt(0)" ::: "memory");
      __hip_atomic_fetch_add((u32*)(tg + TG_FIN), 1u, __ATOMIC_RELAXED,
                             __HIP_MEMORY_SCOPE_AGENT);
      if (lvl == 3) {
        int spin = 0;
        while (uload((u32*)(tg + TG_FIN)) < (u32)NLVL) {
          __builtin_amdgcn_s_sleep(1);
          if (++spin > POLL_CAP) break;
        }
        float s = 0.f;
        for (int k = 0; k < NLVL; ++k)
          s += gload((float*)(tg + TG_FE + (size_t)k * 8));
        out[2 * NLVL * HDIM] = s;
      }
    }
  } else {
    // ================= square matvec phases =================
    const int wid = wgl * NWAVES + wave;        // 0..63
    const int base = wid * 16;
    uint2 Wr[16][4];
    const u16* Wb = nullptr; const float* Wf = nullptr;
    const float* bvec = nullptr;
    if (phase == 0)      { Wb = bw + BW_P1 + (size_t)lvl * HDIM * HDIM; Wf = pw1 + (size_t)lvl * HDIM * HDIM; bvec = pb1 + lvl * HDIM; }
    else if (phase == 1) { Wb = bw + BW_P2 + (size_t)lvl * HDIM * HDIM; Wf = pw2 + (size_t)lvl * HDIM * HDIM; bvec = pb2 + lvl * HDIM; }
    else if (phase == 2) { Wb = bw + BW_E1 + (size_t)lvl * HDIM * HDIM; Wf = ew1 + (size_t)lvl * HDIM * HDIM; bvec = eb1 + lvl * HDIM; }
    else                 { Wb = bw + BW_E2 + (size_t)lvl * HDIM * HDIM; Wf = ew2 + (size_t)lvl * HDIM * HDIM; bvec = eb2 + lvl * HDIM; }
    loadW16<BF16>(Wr, Wb, base, lane);
    float myb = (lane < 16) ? bvec[base + lane] : 0.f;

    u64* t1l = tg + TG_T1R + (size_t)lvl * 4 * HDIM;
    u64* erl = tg + TG_ERRR + (size_t)lvl * 4 * HDIM;
    u64* t2l = tg + TG_T2R + (size_t)lvl * 4 * HDIM;

    const bool doq = (phase == 2 && wgl == 0 && wave == 0);
    float4 Q0, Q1, Q2, Q3; float qbl = 0.f;
    if (doq) {
      const float4* q4 = (const float4*)(qw + lvl * HDIM);
      Q0 = q4[lane]; Q1 = q4[lane + 64]; Q2 = q4[lane + 128]; Q3 = q4[lane + 192];
      qbl = qb[lvl];
    }

    u32 pc1 = 0, pc2 = 0;
    for (int r = lvl; r < lvl + SEQ; ++r) {
      const int t = r - lvl;
      float* xb = xl[r & 1];
      // --- thread-0 representative pre-scan (congestion control) ---
      if (threadIdx.x == 0) {
        if (phase == 0) {
          pc1 = repscan<32, 32>(
              hsT + (size_t)(((r - 1) & 3) * NLVL + (lvl - 1)) * HDIM, (u32)r, pc1);
        } else if (phase == 1) {
          pc1 = repscan<8, 128>(t1l + (size_t)(r & 3) * HDIM, (u32)(r + 1), pc1);
          pc2 = repscan<8, 128>(
              encT + (size_t)(((r - 1) & 3) * NLVL + (lvl - 1)) * HDIM, (u32)r, pc2);
        } else if (phase == 2) {
          if (lvl > 0)
            pc1 = repscan<8, 128>(erl + (size_t)(r & 3) * HDIM, (u32)(r + 1), pc1);
        } else {
          pc1 = repscan<8, 128>(t2l + (size_t)(r & 3) * HDIM, (u32)(r + 1), pc1);
        }
      }
      __syncthreads();
      // --- single-shot fills ---
      float my_e = 0.f;
      if (phase == 0) {
        fill_x(hsT + (size_t)(((r - 1) & 3) * NLVL + (lvl - 1)) * HDIM, nullptr,
               (u32)r, xb);
        if (threadIdx.x == 0 && t >= 4) gscan<8>(progp(tg, lvl, 1), (u32)(r - 3));
      } else if (phase == 1) {
        fill_x(t1l + (size_t)(r & 3) * HDIM, nullptr, (u32)(r + 1), xb);
        if (lane < 16)
          my_e = tval(pollt(encT + (size_t)(((r - 1) & 3) * NLVL + (lvl - 1)) * HDIM +
                                base + lane, (u32)r));
        if (threadIdx.x == 0 && t >= 4) gscan<8>(progp(tg, lvl, 2), (u32)(r - 3));
      } else if (phase == 2) {
        if (lvl == 0) fill_x(nullptr, observed + (size_t)t * HDIM, 0u, xb);
        else          fill_x(erl + (size_t)(r & 3) * HDIM, nullptr, (u32)(r + 1), xb);
        if (threadIdx.x == 0 && t >= 4) {
          gscan<8>(progp(tg, lvl, 3), (u32)(r - 3));
          gscan<32>(progp(tg, lvl, 4), (u32)(r - 3));
        }
      } else {
        fill_x(t2l + (size_t)(r & 3) * HDIM, nullptr, (u32)(r + 1), xb);
        if (threadIdx.x == 0 && t >= 4) {
          gscan<32>(progp(tg, lvl, 4), (u32)(r - 3));
          if (lvl < 3)
            gscan<8>(progp(tg, lvl + 1, 1), (u32)(r - 2));
        }
      }
      __syncthreads();
      if (threadIdx.x == 0) pub(myprog, (u32)(r + 1));
      // --- compute ---
      float o = dot16_keep<BF16>(Wr, Wf, base, (const float4*)xb, lane);
      // --- stores ---
      if (phase == 0) {
        if (lane < 16)
          tstore(t1l + (size_t)(r & 3) * HDIM + base + lane, gelu_f(o + myb),
                 (u32)(r + 1));
      } else if (phase == 1) {
        if (lane < 16) {
          float p = o + myb;
          tstore(erl + (size_t)(r & 3) * HDIM + base + lane, my_e - p, (u32)(r + 1));
          if (t == SEQ - 1) out[lvl * HDIM + base + lane] = p;
        }
      } else if (phase == 2) {
        if (lane < 16)
          tstore(t2l + (size_t)(r & 3) * HDIM + base + lane, gelu_f(o + myb),
                 (u32)(r + 1));
        if (doq) {
          const float4* x4 = (const float4*)xb;
          float d = dot4f(Q0, x4[lane], 0.f);
          d = dot4f(Q1, x4[lane + 64], d);
          d = dot4f(Q2, x4[lane + 128], d);
          d = dot4f(Q3, x4[lane + 192], d);
          d = wredux_all(d);
          if (lane == 0)
            tstore(tg + TG_DPR + ((size_t)lvl * 4 + (r & 3)) * 8, d + qbl,
                   (u32)(r + 1));
        }
        if (lvl == 0 && t == SEQ - 1) {
          int i = wgl * THREADS + threadIdx.x;
          if (i < HDIM) out[i] = 0.f;
        }
      } else {
        if (lane < 16) {
          float e = o + myb;
          tstore(encT + (size_t)((r & 3) * NLVL + lvl) * HDIM + base + lane, e,
                 (u32)(r + 1));
          if (t == SEQ - 1) out[NLVL * HDIM + lvl * HDIM + base + lane] = e;
        }
      }
    }
  }
}

extern "C" void kernel_launch(void* const* d_in, const int* in_sizes, int n_in,
                              void* d_out, int out_size, void* d_ws, size_t ws_size,
                              hipStream_t stream) {
  const float* observed = (const float*)d_in[0];
  const float* pw1 = (const float*)d_in[1];
  const float* pb1 = (const float*)d_in[2];
  const float* pw2 = (const float*)d_in[3];
  const float* pb2 = (const float*)d_in[4];
  const float* ew1 = (const float*)d_in[5];
  const float* eb1 = (const float*)d_in[6];
  const float* ew2 = (const float*)d_in[7];
  const float* eb2 = (const float*)d_in[8];
  const float* qw  = (const float*)d_in[9];
  const float* qb  = (const float*)d_in[10];
  const float* wih = (const float*)d_in[11];
  // d_in[12] = whh — unused (h0 == 0 per step)
  const float* bih = (const float*)d_in[13];
  const float* bhh = (const float*)d_in[14];
  float* out = (float*)d_out;
  u64* tg = (u64*)d_ws;
  u16* bw = (u16*)((char*)d_ws + (size_t)TG_END * 8);

  const size_t need = (size_t)TG_END * 8 + (size_t)BW_TOTAL * 2;
  const bool use_bf16 = (ws_size >= need);

  hipLaunchKernelGGL(tpn_init, dim3(64), dim3(256), 0, stream, tg);

  if (use_bf16) {
    const int nsq = NLVL * HDIM * HDIM;
    hipLaunchKernelGGL(cvt_sq, dim3(512), dim3(256), 0, stream, pw1, bw + BW_P1, nsq);
    hipLaunchKernelGGL(cvt_sq, dim3(512), dim3(256), 0, stream, pw2, bw + BW_P2, nsq);
    hipLaunchKernelGGL(cvt_sq, dim3(512), dim3(256), 0, stream, ew1, bw + BW_E1, nsq);
    hipLaunchKernelGGL(cvt_sq, dim3(512), dim3(256), 0, stream, ew2, bw + BW_E2, nsq);
    hipLaunchKernelGGL(cvt_ih, dim3(512), dim3(256), 0, stream, wih, bw + BW_IH);
  }

  const u16* bwc = bw;
  void* args[] = { &observed, &pw1, &pb1, &pw2, &pb2, &ew1, &eb1, &ew2, &eb2,
                   &qw, &qb, &wih, &bih, &bhh, &out, &tg, &bwc };
  if (use_bf16) {
    (void)hipLaunchCooperativeKernel((void*)tpn_main_t<true>, dim3(NWG),
                                     dim3(THREADS), args, 0, stream);
  } else {
    (void)hipLaunchCooperativeKernel((void*)tpn_main_t<false>, dim3(NWG),
                                     dim3(THREADS), args, 0, stream);
  }
}

// Round 7
// 5238.721 us; speedup vs baseline: 1.4871x; 1.4871x over previous
//
#include <hip/hip_runtime.h>
#include <math.h>

// TemporalPredictionNetwork: L=4, S=512, H=1024, B=1.
// Round-12: round-8 verified stage-parallel dataflow + two latency fixes.
// Round-11 post-mortem: serial thread-0 pre-scans REGRESSED (6.9->7.6ms) ->
// round-8's all-thread retries were nearly never taken -> bottleneck is
// serial LATENCY, not poll congestion. Two serial-latency sources fixed:
// (a) RING DEPTH 4 -> 16: WAR guard cycles (e.g. P5[0]@r -> P1[1]fill@(r-2)
//     -> h[0]@(r-3)) had only 3 rounds of slack; deep rings amortize those
//     multi-hop cycles over 15 rounds (~5x less per-round stall) and let
//     level-0's loop-free P3/P4 run 15 rounds ahead (jitter absorption).
// (b) BATCHED first-shot loads: pollt was load->branch->load; P5's fill did
//     5 dependent fabric round trips even when ready. Now all independent
//     tagged loads issue back-to-back, branch after (1 round trip), pollt
//     retry only as slow path. gscan minima cached (scan ~1/13 rounds).
// Producer semantics, dependency edges, WG layout identical to round-8.
// All spins bounded: a sync bug ends as a wrong answer, never a hang.
#define NLVL 4
#define HDIM 1024
#define SEQ  512
#define THREADS 512
#define NWAVES (THREADS / 64)
#define NWG (48 + 3 * 64)    // lvl0: 8+8+32; lvl1-3: 8+8+8+8+32
#define RD 16                // ring depth
#define RM (RD - 1)

typedef unsigned short u16;
typedef unsigned int   u32;
typedef unsigned long long u64;

// ---- tagged workspace layout (u64 units) ----
// entry = {value f32 in [31:0], tag u32 in [63:32]}; round-r write -> tag r+1
#define TG_HS   0                          // [RD][NLVL][HDIM]
#define TG_ENC  (TG_HS + RD*NLVL*HDIM)     // [RD][NLVL][HDIM]
#define TG_T1R  (TG_ENC + RD*NLVL*HDIM)    // [NLVL][RD][HDIM]
#define TG_ERRR (TG_T1R + NLVL*RD*HDIM)
#define TG_T2R  (TG_ERRR + NLVL*RD*HDIM)
#define TG_DPR  (TG_T2R + NLVL*RD*HDIM)    // [NLVL][RD] slots, 8-u64 stride
#define TG_PROG (TG_DPR + NLVL*RD*8)       // [20 groups][32 wgs], 8-u64 stride
#define TG_FE   (TG_PROG + 20*32*8)        // [NLVL][8]
#define TG_FIN  (TG_FE + NLVL*8)
#define TG_END  (TG_FIN + 8)

// bf16 weight region (u16 units) at byte offset TG_END*8
#define BW_SQ   (NLVL * HDIM * HDIM)
#define BW_P1   0
#define BW_P2   (BW_P1 + BW_SQ)
#define BW_E1   (BW_P2 + BW_SQ)
#define BW_E2   (BW_E1 + BW_SQ)
#define BW_IH   (BW_E2 + BW_SQ)            // L x 3H x H (gates i,g,o)
#define BW_IH_N (NLVL * 3 * HDIM * HDIM)
#define BW_TOTAL (BW_IH + BW_IH_N)

#define POLL_CAP  (1 << 16)                // ~30 ms worst case
#define GSCAN_CAP (1 << 13)                // ~2 ms worst case

__device__ __forceinline__ float gelu_f(float x) {
  return 0.5f * x * (1.0f + erff(x * 0.70710678118654752f));
}
__device__ __forceinline__ float sigmoid_f(float x) {
  return 1.0f / (1.0f + __expf(-x));
}

__device__ __forceinline__ float gload(const float* p) {
  return __hip_atomic_load((float*)p, __ATOMIC_RELAXED, __HIP_MEMORY_SCOPE_AGENT);
}
__device__ __forceinline__ void gstore(float* p, float v) {
  __hip_atomic_store(p, v, __ATOMIC_RELAXED, __HIP_MEMORY_SCOPE_AGENT);
}
__device__ __forceinline__ u32 uload(const u32* p) {
  return __hip_atomic_load((u32*)p, __ATOMIC_RELAXED, __HIP_MEMORY_SCOPE_AGENT);
}
__device__ __forceinline__ u64 tload(const u64* p) {
  return __hip_atomic_load((u64*)p, __ATOMIC_RELAXED, __HIP_MEMORY_SCOPE_AGENT);
}
__device__ __forceinline__ void tstore(u64* p, float v, u32 tag) {
  u64 x = ((u64)tag << 32) | (u64)__float_as_uint(v);
  __hip_atomic_store(p, x, __ATOMIC_RELAXED, __HIP_MEMORY_SCOPE_AGENT);
}
__device__ __forceinline__ float tval(u64 x) { return __uint_as_float((u32)x); }
__device__ __forceinline__ u32   ttag(u64 x) { return (u32)(x >> 32); }

// slow-path tag poll (first-shot load done by caller, batched)
__device__ __forceinline__ u64 pollt(const u64* p, u32 need) {
  int spin = 0;
  for (;;) {
    u64 x = tload(p);
    if (ttag(x) >= need) return x;
    if (++spin > 16) {
      __builtin_amdgcn_s_sleep(1);
      if (spin > POLL_CAP) return x;
    }
  }
}

// min-scan guard over a consumer group's progress words, cached:
// satisfied edges cost zero loads; unsatisfied ones rescan until min >= need.
template <int N>
__device__ __forceinline__ u32 gscan_min(const u64* pb, u32 need, u32 cached) {
  if (cached >= need) return cached;
  int spin = 0;
  for (;;) {
    u32 mn = 0xffffffffu;
#pragma unroll
    for (int w = 0; w < N; ++w) {
      u32 c = uload((const u32*)(pb + (size_t)w * 8));
      mn = (c < mn) ? c : mn;
    }
    if (mn >= need) return mn;
    __builtin_amdgcn_s_sleep(2);
    if (++spin > GSCAN_CAP) return need;   // bounded: never hang
  }
}

__device__ __forceinline__ float wredux_all(float v) {   // butterfly: all lanes get sum
#pragma unroll
  for (int off = 32; off; off >>= 1) v += __shfl_xor(v, off, 64);
  return v;
}

__device__ __forceinline__ float dot4f(float4 a, float4 x, float acc) {
  return fmaf(a.x, x.x, fmaf(a.y, x.y, fmaf(a.z, x.z, fmaf(a.w, x.w, acc))));
}
__device__ __forceinline__ float bflo(u32 u) { return __uint_as_float(u << 16); }
__device__ __forceinline__ float bfhi(u32 u) { return __uint_as_float(u & 0xffff0000u); }
__device__ __forceinline__ float bdot(uint2 u, float4 x, float acc) {
  acc = fmaf(bflo(u.x), x.x, acc); acc = fmaf(bfhi(u.x), x.y, acc);
  acc = fmaf(bflo(u.y), x.z, acc); acc = fmaf(bfhi(u.y), x.w, acc);
  return acc;
}
__device__ __forceinline__ u16 f2bf(float f) {
  u32 b = __float_as_uint(f);
  return (u16)((b + 0x7fffu + ((b >> 16) & 1u)) >> 16);
}

// fill LDS x-vector from tagged (st) or plain (sp) 1024-vector.
// Batched first-shot: both loads issue before either check.
__device__ __forceinline__ void fill_x(const u64* st, const float* sp, u32 need,
                                       float* xb) {
  const int i0 = threadIdx.x, i1 = threadIdx.x + THREADS;
  float v0, v1;
  if (st) {
    u64 A = tload(st + i0);
    u64 B = tload(st + i1);
    if (ttag(A) < need) A = pollt(st + i0, need);
    if (ttag(B) < need) B = pollt(st + i1, need);
    v0 = tval(A); v1 = tval(B);
  } else {
    v0 = sp[i0]; v1 = sp[i1];
  }
  xb[i0] = v0; xb[i1] = v1;
}

template <bool BF16>
__device__ __forceinline__ void loadW16(uint2 (&Wr)[16][4], const u16* Wb,
                                        int base, int lane) {
  if constexpr (BF16) {
#pragma unroll
    for (int k = 0; k < 16; ++k) {
      const uint2* w = (const uint2*)(Wb + (size_t)(base + k) * HDIM);
      Wr[k][0] = w[lane]; Wr[k][1] = w[lane + 64];
      Wr[k][2] = w[lane + 128]; Wr[k][3] = w[lane + 192];
    }
  }
}

// 16-row matvec; returns o_j in lane j (j<16)
template <bool BF16>
__device__ __forceinline__ float dot16_keep(const uint2 (&Wr)[16][4],
                                            const float* Wf, int base,
                                            const float4* x4, int lane) {
  float4 X0 = x4[lane], X1 = x4[lane + 64], X2 = x4[lane + 128], X3 = x4[lane + 192];
  float keep = 0.f;
#pragma unroll
  for (int k = 0; k < 16; ++k) {
    float a;
    if constexpr (BF16) {
      a = bdot(Wr[k][0], X0, 0.f); a = bdot(Wr[k][1], X1, a);
      a = bdot(Wr[k][2], X2, a);  a = bdot(Wr[k][3], X3, a);
    } else {
      const float4* w = (const float4*)(Wf + (size_t)(base + k) * HDIM);
      float4 A0 = w[lane], A1 = w[lane + 64], A2 = w[lane + 128], A3 = w[lane + 192];
      a = dot4f(A0, X0, 0.f); a = dot4f(A1, X1, a);
      a = dot4f(A2, X2, a);   a = dot4f(A3, X3, a);
    }
    a = wredux_all(a);
    keep = (lane == k) ? a : keep;
  }
  return keep;
}

extern "C" __global__ void tpn_init(u64* tg) {
  int i = blockIdx.x * blockDim.x + threadIdx.x;
  int n = blockDim.x * gridDim.x;
  // hs: value 0, tag = lvl (satisfies P5@r=lvl reading zero initial state;
  // all later readers need larger tags). Layout [RD][NLVL][HDIM].
  for (int k = i; k < RD * NLVL * HDIM; k += n) {
    u32 lvl = (u32)((k / HDIM) % NLVL);
    tg[TG_HS + k] = ((u64)lvl) << 32;
  }
  for (int k = i; k < RD * NLVL * HDIM; k += n) tg[TG_ENC + k] = 0ull;
  for (int k = i; k < 3 * NLVL * RD * HDIM; k += n) tg[TG_T1R + k] = 0ull; // t1,err,t2
  for (int k = i; k < (TG_END - TG_DPR); k += n) tg[TG_DPR + k] = 0ull;
}

extern "C" __global__ void cvt_sq(const float* __restrict__ src,
                                  u16* __restrict__ dst, int n) {
  int i = blockIdx.x * blockDim.x + threadIdx.x;
  int stride = blockDim.x * gridDim.x;
  for (; i < n; i += stride) dst[i] = f2bf(src[i]);
}

// wih [L][4H][H] -> compact [L][3H][H] keeping gates {i=0, g=2, o=3}
extern "C" __global__ void cvt_ih(const float* __restrict__ wih,
                                  u16* __restrict__ dst) {
  int i = blockIdx.x * blockDim.x + threadIdx.x;
  int stride = blockDim.x * gridDim.x;
  const int per_lvl = 3 * HDIM * HDIM;
  for (; i < NLVL * per_lvl; i += stride) {
    int l = i / per_lvl;
    int rem = i - l * per_lvl;
    int gd = rem / (HDIM * HDIM);
    int rr = rem - gd * (HDIM * HDIM);
    int gs = (gd == 0) ? 0 : gd + 1;
    dst[i] = f2bf(wih[((size_t)(l * 4 + gs) * HDIM) * HDIM + rr]);
  }
}

__device__ __forceinline__ u64* progp(u64* tg, int l, int ph) {
  return tg + TG_PROG + ((size_t)(l * 5 + ph) * 32) * 8;
}
__device__ __forceinline__ void pub(u64* w, u32 v) {
  __hip_atomic_store((u32*)w, v, __ATOMIC_RELAXED, __HIP_MEMORY_SCOPE_AGENT);
}

template <bool BF16>
__global__ void __launch_bounds__(THREADS) tpn_main_t(
    const float* __restrict__ observed,
    const float* __restrict__ pw1, const float* __restrict__ pb1,
    const float* __restrict__ pw2, const float* __restrict__ pb2,
    const float* __restrict__ ew1, const float* __restrict__ eb1,
    const float* __restrict__ ew2, const float* __restrict__ eb2,
    const float* __restrict__ qw,  const float* __restrict__ qb,
    const float* __restrict__ wih, const float* __restrict__ bih,
    const float* __restrict__ bhh,
    float* __restrict__ out, u64* __restrict__ tg,
    const u16* __restrict__ bw)
{
  __shared__ __align__(16) float xl[2][HDIM];
  __shared__ float sred[NWAVES];
  const int bx = blockIdx.x;
  int lvl, phase, wgl;
  if (bx < 48) {
    lvl = 0;
    if (bx < 8)       { phase = 2; wgl = bx; }
    else if (bx < 16) { phase = 3; wgl = bx - 8; }
    else              { phase = 4; wgl = bx - 16; }
  } else {
    int b = bx - 48; lvl = 1 + b / 64; int o = b % 64;
    if (o < 8)       { phase = 0; wgl = o; }
    else if (o < 16) { phase = 1; wgl = o - 8; }
    else if (o < 24) { phase = 2; wgl = o - 16; }
    else if (o < 32) { phase = 3; wgl = o - 24; }
    else             { phase = 4; wgl = o - 32; }
  }
  const int wave = threadIdx.x >> 6, lane = threadIdx.x & 63;

  u64* hsT  = tg + TG_HS;
  u64* encT = tg + TG_ENC;
  u64* myprog = progp(tg, lvl, phase) + (size_t)wgl * 8;

  if (phase == 4) {
    // ================= P5: LSTM h-chain =================
    const int wid = wgl * NWAVES + wave;        // 0..255
    const int b4 = wid * 4;                     // 4 h-rows per wave
    const u16* Bih = bw + BW_IH + (size_t)lvl * 3 * HDIM * HDIM;
    const float* Wih = wih + (size_t)lvl * 4 * HDIM * HDIM;
    const float* bi = bih + lvl * 4 * HDIM;
    const float* bh = bhh + lvl * 4 * HDIM;
    uint2 Wr[12][4];
    if constexpr (BF16) {
#pragma unroll
      for (int k = 0; k < 12; ++k) {
        const int hr = k / 3, g = k % 3;
        const uint2* w = (const uint2*)(Bih + ((size_t)g * HDIM + b4 + hr) * HDIM);
        Wr[k][0] = w[lane]; Wr[k][1] = w[lane + 64];
        Wr[k][2] = w[lane + 128]; Wr[k][3] = w[lane + 192];
      }
    }
    float mb0 = 0.f, mb1 = 0.f, mb2 = 0.f;
    if (lane < 4) {
      const int rr = b4 + lane;
      mb0 = bi[rr] + bh[rr];
      mb1 = bi[2 * HDIM + rr] + bh[2 * HDIM + rr];
      mb2 = bi[3 * HDIM + rr] + bh[3 * HDIM + rr];
    }
    float fe_local = 0.f;
    u32 c_own = 0, c_p1a = 0;
    for (int r = lvl; r < lvl + SEQ; ++r) {
      float* xb = xl[r & 1];
      const u64* el = encT + (size_t)((r & RM) * NLVL + lvl) * HDIM;
      const u64* hold = hsT + (size_t)(((r - 1) & RM) * NLVL + lvl) * HDIM;
      const u64* dps = tg + TG_DPR + ((size_t)lvl * RD + (r & RM)) * 8;
      // --- WAR guards (thread0, cached; fire ~1/13 rounds) ---
      if (threadIdx.x == 0 && r - lvl >= RD) {
        c_own = gscan_min<32>(progp(tg, lvl, 4), (u32)(r - RD + 2), c_own);
        if (lvl < 3)
          c_p1a = gscan_min<8>(progp(tg, lvl + 1, 0), (u32)(r - RD + 2), c_p1a);
      }
      // --- batched first-shot loads (5 independent round trips -> 1) ---
      const int i0 = threadIdx.x, i1 = threadIdx.x + THREADS;
      u64 E0 = tload(el + i0);
      u64 E1 = tload(el + i1);
      u64 H0 = tload(hold + i0);
      u64 H1 = tload(hold + i1);
      u64 D  = tload(dps);
      if (ttag(E0) < (u32)(r + 1)) E0 = pollt(el + i0, (u32)(r + 1));
      if (ttag(E1) < (u32)(r + 1)) E1 = pollt(el + i1, (u32)(r + 1));
      if (ttag(H0) < (u32)r)       H0 = pollt(hold + i0, (u32)r);
      if (ttag(H1) < (u32)r)       H1 = pollt(hold + i1, (u32)r);
      if (ttag(D)  < (u32)(r + 1)) D  = pollt(dps, (u32)(r + 1));
      float pr = sigmoid_f(tval(D));
      float e0 = tval(E0), e1 = tval(E1);
      xb[i0] = fmaf(pr, e0, tval(H0));
      xb[i1] = fmaf(pr, e1, tval(H1));
      __syncthreads();
      if (threadIdx.x == 0) pub(myprog, (u32)(r + 1));
      // --- compute ---
      const float4* x4 = (const float4*)xb;
      float4 X0 = x4[lane], X1 = x4[lane + 64], X2 = x4[lane + 128], X3 = x4[lane + 192];
      float dk0 = 0.f, dk1 = 0.f, dk2 = 0.f;
#pragma unroll
      for (int k = 0; k < 12; ++k) {
        const int hr = k / 3, g = k % 3;
        float a;
        if constexpr (BF16) {
          a = bdot(Wr[k][0], X0, 0.f); a = bdot(Wr[k][1], X1, a);
          a = bdot(Wr[k][2], X2, a);  a = bdot(Wr[k][3], X3, a);
        } else {
          const int gsel = (g == 0) ? 0 : (g + 1);
          const float4* w =
              (const float4*)(Wih + ((size_t)gsel * HDIM + b4 + hr) * HDIM);
          float4 A0 = w[lane], A1 = w[lane + 64], A2 = w[lane + 128], A3 = w[lane + 192];
          a = dot4f(A0, X0, 0.f); a = dot4f(A1, X1, a);
          a = dot4f(A2, X2, a);   a = dot4f(A3, X3, a);
        }
        a = wredux_all(a);
        if (g == 0)      dk0 = (lane == hr) ? a : dk0;
        else if (g == 1) dk1 = (lane == hr) ? a : dk1;
        else             dk2 = (lane == hr) ? a : dk2;
      }
      if (lane < 4) {
        float gi = sigmoid_f(dk0 + mb0);
        float gg = tanhf(dk1 + mb1);
        float go = sigmoid_f(dk2 + mb2);
        tstore(hsT + (size_t)((r & RM) * NLVL + lvl) * HDIM + b4 + lane,
               go * tanhf(gi * gg), (u32)(r + 1));
      }
      if (wgl == 0) {   // fe += prec * sum(enc^2)
        float s = fmaf(e0, e0, e1 * e1);
        s = wredux_all(s);
        if (lane == 0) sred[wave] = s;
        __syncthreads();
        if (threadIdx.x == 0) {
          float tot = 0.f;
#pragma unroll
          for (int k = 0; k < NWAVES; ++k) tot += sred[k];
          fe_local += pr * tot;
        }
        __syncthreads();
      }
    }
    if (wgl == 0 && threadIdx.x == 0) {
      gstore((float*)(tg + TG_FE + (size_t)lvl * 8), fe_local);
      asm volatile("s_waitcnt vmcnt(0)" ::: "memory");
      __hip_atomic_fetch_add((u32*)(tg + TG_FIN), 1u, __ATOMIC_RELAXED,
                             __HIP_MEMORY_SCOPE_AGENT);
      if (lvl == 3) {
        int spin = 0;
        while (uload((u32*)(tg + TG_FIN)) < (u32)NLVL) {
          __builtin_amdgcn_s_sleep(1);
          if (++spin > POLL_CAP) break;
        }
        float s = 0.f;
        for (int k = 0; k < NLVL; ++k)
          s += gload((float*)(tg + TG_FE + (size_t)k * 8));
        out[2 * NLVL * HDIM] = s;
      }
    }
  } else {
    // ================= square matvec phases =================
    const int wid = wgl * NWAVES + wave;        // 0..63
    const int base = wid * 16;
    uint2 Wr[16][4];
    const u16* Wb = nullptr; const float* Wf = nullptr;
    const float* bvec = nullptr;
    if (phase == 0)      { Wb = bw + BW_P1 + (size_t)lvl * HDIM * HDIM; Wf = pw1 + (size_t)lvl * HDIM * HDIM; bvec = pb1 + lvl * HDIM; }
    else if (phase == 1) { Wb = bw + BW_P2 + (size_t)lvl * HDIM * HDIM; Wf = pw2 + (size_t)lvl * HDIM * HDIM; bvec = pb2 + lvl * HDIM; }
    else if (phase == 2) { Wb = bw + BW_E1 + (size_t)lvl * HDIM * HDIM; Wf = ew1 + (size_t)lvl * HDIM * HDIM; bvec = eb1 + lvl * HDIM; }
    else                 { Wb = bw + BW_E2 + (size_t)lvl * HDIM * HDIM; Wf = ew2 + (size_t)lvl * HDIM * HDIM; bvec = eb2 + lvl * HDIM; }
    loadW16<BF16>(Wr, Wb, base, lane);
    float myb = (lane < 16) ? bvec[base + lane] : 0.f;

    u64* t1l = tg + TG_T1R + (size_t)lvl * RD * HDIM;
    u64* erl = tg + TG_ERRR + (size_t)lvl * RD * HDIM;
    u64* t2l = tg + TG_T2R + (size_t)lvl * RD * HDIM;

    const bool doq = (phase == 2 && wgl == 0 && wave == 0);
    float4 Q0, Q1, Q2, Q3; float qbl = 0.f;
    if (doq) {
      const float4* q4 = (const float4*)(qw + lvl * HDIM);
      Q0 = q4[lane]; Q1 = q4[lane + 64]; Q2 = q4[lane + 128]; Q3 = q4[lane + 192];
      qbl = qb[lvl];
    }

    u32 c_w = 0, c_w2 = 0;
    for (int r = lvl; r < lvl + SEQ; ++r) {
      const int t = r - lvl;
      float* xb = xl[r & 1];
      // --- WAR guards (thread0, cached) ---
      if (threadIdx.x == 0 && t >= RD) {
        if (phase == 0) {
          c_w = gscan_min<8>(progp(tg, lvl, 1), (u32)(r - RD + 1), c_w);
        } else if (phase == 1) {
          c_w = gscan_min<8>(progp(tg, lvl, 2), (u32)(r - RD + 1), c_w);
        } else if (phase == 2) {
          c_w  = gscan_min<8>(progp(tg, lvl, 3), (u32)(r - RD + 1), c_w);
          c_w2 = gscan_min<32>(progp(tg, lvl, 4), (u32)(r - RD + 1), c_w2);
        } else {
          c_w = gscan_min<32>(progp(tg, lvl, 4), (u32)(r - RD + 1), c_w);
          if (lvl < 3)
            c_w2 = gscan_min<8>(progp(tg, lvl + 1, 1), (u32)(r - RD + 2), c_w2);
        }
      }
      // --- fills (batched first-shot inside fill_x) ---
      float my_e = 0.f;
      if (phase == 0) {
        fill_x(hsT + (size_t)(((r - 1) & RM) * NLVL + (lvl - 1)) * HDIM, nullptr,
               (u32)r, xb);
      } else if (phase == 1) {
        // batch the enc first-shot with the fill loads
        const u64* ep = encT + (size_t)(((r - 1) & RM) * NLVL + (lvl - 1)) * HDIM +
                        base + lane;
        u64 Epre = 0;
        if (lane < 16) Epre = tload(ep);
        fill_x(t1l + (size_t)(r & RM) * HDIM, nullptr, (u32)(r + 1), xb);
        if (lane < 16) {
          if (ttag(Epre) < (u32)r) Epre = pollt(ep, (u32)r);
          my_e = tval(Epre);
        }
      } else if (phase == 2) {
        if (lvl == 0) fill_x(nullptr, observed + (size_t)t * HDIM, 0u, xb);
        else          fill_x(erl + (size_t)(r & RM) * HDIM, nullptr, (u32)(r + 1), xb);
      } else {
        fill_x(t2l + (size_t)(r & RM) * HDIM, nullptr, (u32)(r + 1), xb);
      }
      __syncthreads();
      if (threadIdx.x == 0) pub(myprog, (u32)(r + 1));
      // --- compute ---
      float o = dot16_keep<BF16>(Wr, Wf, base, (const float4*)xb, lane);
      // --- stores ---
      if (phase == 0) {
        if (lane < 16)
          tstore(t1l + (size_t)(r & RM) * HDIM + base + lane, gelu_f(o + myb),
                 (u32)(r + 1));
      } else if (phase == 1) {
        if (lane < 16) {
          float p = o + myb;
          tstore(erl + (size_t)(r & RM) * HDIM + base + lane, my_e - p, (u32)(r + 1));
          if (t == SEQ - 1) out[lvl * HDIM + base + lane] = p;
        }
      } else if (phase == 2) {
        if (lane < 16)
          tstore(t2l + (size_t)(r & RM) * HDIM + base + lane, gelu_f(o + myb),
                 (u32)(r + 1));
        if (doq) {
          const float4* x4 = (const float4*)xb;
          float d = dot4f(Q0, x4[lane], 0.f);
          d = dot4f(Q1, x4[lane + 64], d);
          d = dot4f(Q2, x4[lane + 128], d);
          d = dot4f(Q3, x4[lane + 192], d);
          d = wredux_all(d);
          if (lane == 0)
            tstore(tg + TG_DPR + ((size_t)lvl * RD + (r & RM)) * 8, d + qbl,
                   (u32)(r + 1));
        }
        if (lvl == 0 && t == SEQ - 1) {
          int i = wgl * THREADS + threadIdx.x;
          if (i < HDIM) out[i] = 0.f;
        }
      } else {
        if (lane < 16) {
          float e = o + myb;
          tstore(encT + (size_t)((r & RM) * NLVL + lvl) * HDIM + base + lane, e,
                 (u32)(r + 1));
          if (t == SEQ - 1) out[NLVL * HDIM + lvl * HDIM + base + lane] = e;
        }
      }
    }
  }
}

extern "C" void kernel_launch(void* const* d_in, const int* in_sizes, int n_in,
                              void* d_out, int out_size, void* d_ws, size_t ws_size,
                              hipStream_t stream) {
  const float* observed = (const float*)d_in[0];
  const float* pw1 = (const float*)d_in[1];
  const float* pb1 = (const float*)d_in[2];
  const float* pw2 = (const float*)d_in[3];
  const float* pb2 = (const float*)d_in[4];
  const float* ew1 = (const float*)d_in[5];
  const float* eb1 = (const float*)d_in[6];
  const float* ew2 = (const float*)d_in[7];
  const float* eb2 = (const float*)d_in[8];
  const float* qw  = (const float*)d_in[9];
  const float* qb  = (const float*)d_in[10];
  const float* wih = (const float*)d_in[11];
  // d_in[12] = whh — unused (h0 == 0 per step)
  const float* bih = (const float*)d_in[13];
  const float* bhh = (const float*)d_in[14];
  float* out = (float*)d_out;
  u64* tg = (u64*)d_ws;
  u16* bw = (u16*)((char*)d_ws + (size_t)TG_END * 8);

  const size_t need = (size_t)TG_END * 8 + (size_t)BW_TOTAL * 2;
  const bool use_bf16 = (ws_size >= need);

  hipLaunchKernelGGL(tpn_init, dim3(64), dim3(256), 0, stream, tg);

  if (use_bf16) {
    const int nsq = NLVL * HDIM * HDIM;
    hipLaunchKernelGGL(cvt_sq, dim3(512), dim3(256), 0, stream, pw1, bw + BW_P1, nsq);
    hipLaunchKernelGGL(cvt_sq, dim3(512), dim3(256), 0, stream, pw2, bw + BW_P2, nsq);
    hipLaunchKernelGGL(cvt_sq, dim3(512), dim3(256), 0, stream, ew1, bw + BW_E1, nsq);
    hipLaunchKernelGGL(cvt_sq, dim3(512), dim3(256), 0, stream, ew2, bw + BW_E2, nsq);
    hipLaunchKernelGGL(cvt_ih, dim3(512), dim3(256), 0, stream, wih, bw + BW_IH);
  }

  const u16* bwc = bw;
  void* args[] = { &observed, &pw1, &pb1, &pw2, &pb2, &ew1, &eb1, &ew2, &eb2,
                   &qw, &qb, &wih, &bih, &bhh, &out, &tg, &bwc };
  if (use_bf16) {
    (void)hipLaunchCooperativeKernel((void*)tpn_main_t<true>, dim3(NWG),
                                     dim3(THREADS), args, 0, stream);
  } else {
    (void)hipLaunchCooperativeKernel((void*)tpn_main_t<false>, dim3(NWG),
                                     dim3(THREADS), args, 0, stream);
  }
}